// Round 11
// baseline (391.644 us; speedup 1.0000x reference)
//
#include <hip/hip_runtime.h>
#include <hip/hip_fp16.h>
#include <math.h>

// Problem constants (from setup_inputs)
#define BB   8
#define CXH  16
#define CXL  8
#define HH   256
#define HL   512

// Tiling
#define TS   32              // 512-res tile edge
#define HALO 2
#define GT   (TS + 2*HALO)   // 36 : LN'd tile + halo
#define NPAIR (GT * GT / 2)  // 648 pixel-pair tasks per tile

// Workspace layout (floats):
//  [0, WS_PATCH)        pre-projected xh, branch-pair interleaved
//  +16   A[8], Bc[8]    folded tail affine
//  +160  W2t[cg][o8]    tail_w * tail_ln_w, transposed (cg-major)
//  +720  wbs            g_wt_w * (0.5*g_wt_s)   [br][c][k][9]
//  +180  bws            g_base_w * g_base_s     [br][c][9]
//  +20   bbs            g_base_b * g_base_s     [br][c]
#define WS_PATCH_FLOATS (BB * 4 * HH * HH * 2)     // 4,194,304 floats = 16 MB
#define WS_AB_OFF       WS_PATCH_FLOATS
#define WS_W2T_OFF      (WS_AB_OFF + 16)
#define WS_WBS_OFF      (WS_W2T_OFF + 160)
#define WS_BWS_OFF      (WS_WBS_OFF + 720)
#define WS_BBS_OFF      (WS_BWS_OFF + 180)
#define WS_TOTAL_FLOATS (WS_BBS_OFF + 20)
#define WS_NEEDED_BYTES ((size_t)WS_TOTAL_FLOATS * sizeof(float))

// Branch-free fast GELU (tanh-form); |delta| vs exact ~1e-3 << 0.155 tol.
__device__ __forceinline__ float gelu_fast(float x) {
    const float u = x * (1.595769122f + 0.071354816f * x * x);
    return x * __builtin_amdgcn_rcpf(1.0f + __expf(-u));
}

// Channels-first LN over 5 values (order identical to all prior rounds).
__device__ __forceinline__ void ln5(float* vv, const float* w, const float* bta) {
    const float u = (vv[0] + vv[1] + vv[2] + vv[3] + vv[4]) * 0.2f;
    float var = 0.f;
    #pragma unroll
    for (int c = 0; c < 5; ++c) { const float d = vv[c] - u; var += d * d; }
    var *= 0.2f;
    const float rstd = rsqrtf(var + 1e-6f);
    #pragma unroll
    for (int c = 0; c < 5; ++c) vv[c] = w[c] * ((vv[c] - u) * rstd) + bta[c];
}

// Bilinear lerp of a pair-interleaved (2-channel) corner set.
__device__ __forceinline__ void bil2(const float* __restrict__ wsp, int cbase,
                                     float fx, float fy, float& o0, float& o1) {
    const float2 q00 = *(const float2*)&wsp[cbase];
    const float2 q01 = *(const float2*)&wsp[cbase + 2];
    const float2 q10 = *(const float2*)&wsp[cbase + 2 * HH];
    const float2 q11 = *(const float2*)&wsp[cbase + 2 * HH + 2];
    {
        const float top = q00.x + fx * (q01.x - q00.x);
        const float bot = q10.x + fx * (q11.x - q10.x);
        o0 = top + fy * (bot - top);
    }
    {
        const float top = q00.y + fx * (q01.y - q00.y);
        const float bot = q10.y + fx * (q11.y - q10.y);
        o1 = top + fy * (bot - top);
    }
}

// ---------------- Prepass: 1x1 projection 16->8 + folded weight tables ----------------
__global__ __launch_bounds__(256)
void pre_project_kernel(const float* __restrict__ xh,
                        const float* __restrict__ pre_w,
                        const float* __restrict__ pre_b,
                        const float* __restrict__ g_base_w,
                        const float* __restrict__ g_base_b,
                        const float* __restrict__ g_base_s,
                        const float* __restrict__ g_wt_w,
                        const float* __restrict__ g_wt_s,
                        const float* __restrict__ tail_ln_w,
                        const float* __restrict__ tail_ln_b,
                        const float* __restrict__ tail_w,
                        const float* __restrict__ tail_b,
                        float* __restrict__ ws)
{
    const int gid = blockIdx.x * 256 + threadIdx.x;   // 524288 = 8*256*256
    const int b   = gid >> 16;
    const int px  = gid & 0xFFFF;
    const float* xp = xh + (b * CXH) * (HH * HH) + px;
    float xv[16];
    #pragma unroll
    for (int c = 0; c < 16; ++c) xv[c] = xp[c * HH * HH];
    #pragma unroll
    for (int br = 0; br < 4; ++br) {
        float a0 = pre_b[2 * br], a1 = pre_b[2 * br + 1];
        #pragma unroll
        for (int c = 0; c < 16; ++c) {
            a0 += pre_w[(2 * br) * 16 + c] * xv[c];
            a1 += pre_w[(2 * br + 1) * 16 + c] * xv[c];
        }
        float2 r; r.x = a0; r.y = a1;
        *(float2*)&ws[((b * 4 + br) * (HH * HH) + px) * 2] = r;
    }
    // Folded weight tables (tiny, one thread each).
    if (gid < 8) {
        const int o = gid;
        float a = 0.f, bb = tail_b[o];
        for (int cg = 0; cg < 20; ++cg) {
            a  += tail_w[o * 20 + cg] * tail_ln_w[cg];
            bb += tail_w[o * 20 + cg] * tail_ln_b[cg];
        }
        ws[WS_AB_OFF + o]     = a;
        ws[WS_AB_OFF + 8 + o] = bb;
    } else if (gid < 8 + 160) {
        const int i = gid - 8;                 // cg*8 + o8
        const int cg = i / 8, o8 = i % 8;
        ws[WS_W2T_OFF + i] = tail_w[o8 * 20 + cg] * tail_ln_w[cg];
    } else if (gid < 8 + 160 + 720) {
        const int i = gid - 168;               // ((br*5+c)*4+k)*9 + wo
        const int wo = i % 9;
        const int rest = i / 9;
        const int k = rest % 4;
        const int bc = rest / 4;
        const int br = bc / 5, c = bc % 5;
        ws[WS_WBS_OFF + i] =
            g_wt_w[br * 180 + (c * 4 + k) * 9 + wo] * (0.5f * g_wt_s[br * 20 + c * 4 + k]);
    } else if (gid < 8 + 160 + 720 + 180) {
        const int i = gid - 888;               // (br*5+c)*9 + wo
        const int wo = i % 9;
        const int bc = i / 9;
        const int br = bc / 5, c = bc % 5;
        ws[WS_BWS_OFF + i] = g_base_w[br * 45 + c * 9 + wo] * g_base_s[bc];
    } else if (gid < 8 + 160 + 720 + 180 + 20) {
        const int i = gid - 1068;              // br*5+c
        ws[WS_BBS_OFF + i] = g_base_b[i] * g_base_s[i];
    }
}

// ---------------- Phase-1 helper: pixel-PAIR LN build (both branches) ----------------
// EDGE=false (interior blocks): bounds check and clamps provably unnecessary.
// Bounds are pair-uniform: gx0 is always even, OOB only at gx0 = -2 or 512.
// LDS tile is stored in FP16 (LN'd values are O(1); quantization error ~1e-3
// RMS through the convs vs 0.155 tolerance) -> 25,920 B -> 6 blocks/CU.
template <bool EDGE>
__device__ __forceinline__ void build_pair_lds(
    __half (&s_h)[2][5][18][18][4],
    int tid, int ty0, int tx0, int mb, int xlb, int pair,
    const float* __restrict__ xl, const float* __restrict__ mask,
    const float* __restrict__ g_ln_w, const float* __restrict__ g_ln_b,
    const float* __restrict__ wsp0, const float* __restrict__ wsp1)
{
    const float SC = (float)(255.0 / 511.0);
    const int plane = HL * HL;
    const float* gwA = g_ln_w + (2 * pair) * 5;
    const float* gbA = g_ln_b + (2 * pair) * 5;
    const float* gwB = g_ln_w + (2 * pair + 1) * 5;
    const float* gbB = g_ln_b + (2 * pair + 1) * 5;

    int r = tid / 18, m = tid % 18;
    for (int task = tid; task < NPAIR; task += 256) {
        const int gy  = ty0 - HALO + r;
        const int gx0 = tx0 - HALO + 2 * m;
        float a0[5] = {0,0,0,0,0}, a1[5] = {0,0,0,0,0};
        float b0[5] = {0,0,0,0,0}, b1[5] = {0,0,0,0,0};
        bool ok = true;
        if (EDGE) ok = (gy >= 0) && (gy < HL) && (gx0 >= 0) && (gx0 < HL);
        if (ok) {
            const float cy = (float)gy * SC;
            int iy0 = (int)cy;
            if (EDGE) iy0 = min(iy0, HH - 2);
            const float fy = cy - (float)iy0;
            const float cx0 = (float)gx0 * SC;
            int ix00 = (int)cx0;
            if (EDGE) ix00 = min(ix00, HH - 2);
            const float fx0 = cx0 - (float)ix00;
            const float cx1 = (float)(gx0 + 1) * SC;
            int ix01 = (int)cx1;
            if (EDGE) ix01 = min(ix01, HH - 2);
            const float fx1 = cx1 - (float)ix01;
            const int c0 = (iy0 * HH + ix00) * 2;
            const int c1 = (iy0 * HH + ix01) * 2;
            const int pix = gy * HL + gx0;
            const float2 mk = *(const float2*)&mask[mb + pix];

            bil2(wsp0, c0, fx0, fy, a0[0], a0[1]);
            bil2(wsp0, c1, fx1, fy, a1[0], a1[1]);
            bil2(wsp1, c0, fx0, fy, b0[0], b0[1]);
            bil2(wsp1, c1, fx1, fy, b1[0], b1[1]);

            const float2 x0 = *(const float2*)&xl[xlb + (4 * pair + 0) * plane + pix];
            const float2 x1 = *(const float2*)&xl[xlb + (4 * pair + 1) * plane + pix];
            const float2 x2 = *(const float2*)&xl[xlb + (4 * pair + 2) * plane + pix];
            const float2 x3 = *(const float2*)&xl[xlb + (4 * pair + 3) * plane + pix];
            a0[2] = x0.x; a1[2] = x0.y; a0[3] = x1.x; a1[3] = x1.y;
            a0[4] = mk.x; a1[4] = mk.y;
            b0[2] = x2.x; b1[2] = x2.y; b0[3] = x3.x; b1[3] = x3.y;
            b0[4] = mk.x; b1[4] = mk.y;

            ln5(a0, gwA, gbA); ln5(a1, gwA, gbA);
            ln5(b0, gwB, gbB); ln5(b1, gwB, gbB);
        }
        const int qy = r >> 1, sub0 = (r & 1) * 2;
        #pragma unroll
        for (int c = 0; c < 5; ++c)
            *(__half2*)&s_h[0][c][qy][m][sub0] =
                __float22half2_rn(make_float2(a0[c], a1[c]));
        #pragma unroll
        for (int c = 0; c < 5; ++c)
            *(__half2*)&s_h[1][c][qy][m][sub0] =
                __float22half2_rn(make_float2(b0[c], b1[c]));
        // task += 256  ==  r += 14, m += 4  (256 = 14*18 + 4), single wrap
        m += 4; r += 14;
        if (m >= 18) { m -= 18; r += 1; }
    }
}

// ---------------- Main fused kernel: branch-PAIR loop, FP16 LDS ----------------
__global__ __launch_bounds__(256, 3)
void uem_pair_kernel(const float* __restrict__ xl,
                     const float* __restrict__ mask,
                     const float* __restrict__ g_ln_w,
                     const float* __restrict__ g_ln_b,
                     const float* __restrict__ g_pw_w,
                     const float* __restrict__ res_w,
                     const float* __restrict__ res_b,
                     const float* __restrict__ ws,
                     float* __restrict__ out)
{
    __shared__ __align__(16) __half s_h[2][5][18][18][4];   // 25,920 B -> 6 blocks/CU

    const int b   = blockIdx.z;
    const int ty0 = blockIdx.y * TS;
    const int tx0 = blockIdx.x * TS;
    const int tx  = threadIdx.x, ty = threadIdx.y;
    const int tid = ty * 16 + tx;
    const bool edge = (blockIdx.x == 0) || (blockIdx.x == gridDim.x - 1) ||
                      (blockIdx.y == 0) || (blockIdx.y == gridDim.y - 1);

    const int plane = HL * HL;
    const int mb  = b * plane;
    const int xlb = (b * CXL) * plane;

    float S1[4] = {0.f, 0.f, 0.f, 0.f};
    float S2[4] = {0.f, 0.f, 0.f, 0.f};
    float T[4][8];
    #pragma unroll
    for (int p = 0; p < 4; ++p)
        #pragma unroll
        for (int o = 0; o < 8; ++o) T[p][o] = 0.f;

    for (int pair = 0; pair < 2; ++pair) {
        // ---------- Phase 1: LN'd inputs for BOTH branches of the pair ----------
        const float* wsp0 = ws + ((size_t)(b * 4 + 2 * pair)     * (HH * HH)) * 2;
        const float* wsp1 = ws + ((size_t)(b * 4 + 2 * pair + 1) * (HH * HH)) * 2;
        if (edge)
            build_pair_lds<true >(s_h, tid, ty0, tx0, mb, xlb, pair,
                                  xl, mask, g_ln_w, g_ln_b, wsp0, wsp1);
        else
            build_pair_lds<false>(s_h, tid, ty0, tx0, mb, xlb, pair,
                                  xl, mask, g_ln_w, g_ln_b, wsp0, wsp1);
        __syncthreads();

        // ---------- Conv block for each branch of the pair ----------
        for (int s = 0; s < 2; ++s) {
            const int br = 2 * pair + s;
            const float* wbs = ws + WS_WBS_OFF + (size_t)(br * 5) * 36;
            const float* bws = ws + WS_BWS_OFF + (size_t)(br * 5) * 9;
            const float* bbs = ws + WS_BBS_OFF + br * 5;
            float gi[5][4];
            #pragma unroll
            for (int c = 0; c < 5; ++c) {
                // 6x6 patch via 9 b64 quad reads (4 halves each) + cvt
                float P[6][6];
                #pragma unroll
                for (int a = 0; a < 3; ++a)
                    #pragma unroll
                    for (int bq = 0; bq < 3; ++bq) {
                        const float2 raw = *(const float2*)&s_h[s][c][ty + a][tx + bq][0];
                        const float2 f01 = __half22float2(*(const __half2*)&raw.x);
                        const float2 f23 = __half22float2(*(const __half2*)&raw.y);
                        P[2 * a][2 * bq]         = f01.x;
                        P[2 * a][2 * bq + 1]     = f01.y;
                        P[2 * a + 1][2 * bq]     = f23.x;
                        P[2 * a + 1][2 * bq + 1] = f23.y;
                    }
                // Haar butterflies + dwconv with PRE-SCALED weights (wbs):
                // t_k = sum( wbs_k * butterfly_k ), wbs = wt_w * 0.5 * wt_s.
                const float* wc = wbs + c * 36;
                float t0 = 0.f, t1 = 0.f, t2 = 0.f, t3 = 0.f;
                #pragma unroll
                for (int dy = 0; dy < 3; ++dy) {
                    #pragma unroll
                    for (int dx = 0; dx < 3; ++dx) {
                        const float a  = P[2 * dy][2 * dx];
                        const float b2 = P[2 * dy][2 * dx + 1];
                        const float c2 = P[2 * dy + 1][2 * dx];
                        const float d2 = P[2 * dy + 1][2 * dx + 1];
                        const float s0 = a + b2, s1 = c2 + d2;
                        const float d0 = a - b2, d1 = c2 - d2;
                        const int wo = dy * 3 + dx;
                        t0 += wc[wo]      * (s0 + s1);   // LL
                        t1 += wc[9 + wo]  * (s0 - s1);   // LH
                        t2 += wc[18 + wo] * (d0 + d1);   // HL
                        t3 += wc[27 + wo] * (d0 - d1);   // HH
                    }
                }
                const float xt0 = 0.5f * (t0 + t1 + t2 + t3);
                const float xt1 = 0.5f * (t0 + t1 - t2 - t3);
                const float xt2 = 0.5f * (t0 - t1 + t2 - t3);
                const float xt3 = 0.5f * (t0 - t1 - t2 + t3);
                // Base 3x3 dwconv with PRE-SCALED weights, bias-initialized acc.
                const float* bwc = bws + c * 9;
                const float bc = bbs[c];
                #pragma unroll
                for (int p = 0; p < 4; ++p) {
                    const int py = p >> 1, px = p & 1;
                    float acc = bc;
                    #pragma unroll
                    for (int dy = 0; dy < 3; ++dy)
                        #pragma unroll
                        for (int dx = 0; dx < 3; ++dx)
                            acc += bwc[dy * 3 + dx] * P[1 + py + dy][1 + px + dx];
                    const float xtv = (p == 0) ? xt0 : (p == 1) ? xt1 : (p == 2) ? xt2 : xt3;
                    gi[c][p] = acc + xtv;
                }
            }

            // ---------- 5x5 pointwise + tail accumulation (W2t pre-folded) ----------
            #pragma unroll
            for (int o = 0; o < 5; ++o) {
                const int cg = br * 5 + o;
                float v[4];
                #pragma unroll
                for (int p = 0; p < 4; ++p) {
                    float vv = 0.f;
                    #pragma unroll
                    for (int c = 0; c < 5; ++c) vv += g_pw_w[br * 25 + o * 5 + c] * gi[c][p];
                    v[p] = vv;
                    S1[p] += vv;
                    S2[p] += vv * vv;
                }
                const float* w2 = ws + WS_W2T_OFF + cg * 8;   // 8 consecutive floats
                #pragma unroll
                for (int o8 = 0; o8 < 8; ++o8) {
                    const float w = w2[o8];
                    T[0][o8] += w * v[0];
                    T[1][o8] += w * v[1];
                    T[2][o8] += w * v[2];
                    T[3][o8] += w * v[3];
                }
            }
        }
        if (pair == 0) __syncthreads();
    }

    // ---------- Phase 5: tail LN (closed form) + 1x1 + GELU + residual ----------
    float A[8], Bc[8];
    {
        const float4 a0 = *(const float4*)&ws[WS_AB_OFF];
        const float4 a1 = *(const float4*)&ws[WS_AB_OFF + 4];
        const float4 b0 = *(const float4*)&ws[WS_AB_OFF + 8];
        const float4 b1 = *(const float4*)&ws[WS_AB_OFF + 12];
        A[0]=a0.x; A[1]=a0.y; A[2]=a0.z; A[3]=a0.w;
        A[4]=a1.x; A[5]=a1.y; A[6]=a1.z; A[7]=a1.w;
        Bc[0]=b0.x; Bc[1]=b0.y; Bc[2]=b0.z; Bc[3]=b0.w;
        Bc[4]=b1.x; Bc[5]=b1.y; Bc[6]=b1.z; Bc[7]=b1.w;
    }

    #pragma unroll
    for (int py = 0; py < 2; ++py) {
        const int p0 = py * 2, p1 = py * 2 + 1;
        const int gy  = ty0 + 2 * ty + py;
        const int gx0 = tx0 + 2 * tx;
        const float u0    = S1[p0] * 0.05f;
        const float u1    = S1[p1] * 0.05f;
        const float rstd0 = rsqrtf(S2[p0] * 0.05f - u0 * u0 + 1e-6f);
        const float rstd1 = rsqrtf(S2[p1] * 0.05f - u1 * u1 + 1e-6f);

        const int xbase = xlb + gy * HL + gx0;
        float2 xlv[8];
        #pragma unroll
        for (int c = 0; c < 8; ++c) xlv[c] = *(const float2*)&xl[xbase + c * plane];
        const float2 mk = *(const float2*)&mask[mb + gy * HL + gx0];

        #pragma unroll
        for (int o = 0; o < 8; ++o) {
            const float val0 = (T[p0][o] - u0 * A[o]) * rstd0 + Bc[o];
            const float val1 = (T[p1][o] - u1 * A[o]) * rstd1 + Bc[o];
            float r0 = res_b[o] + res_w[o * 9 + 8] * mk.x;
            float r1 = res_b[o] + res_w[o * 9 + 8] * mk.y;
            #pragma unroll
            for (int c = 0; c < 8; ++c) {
                r0 += res_w[o * 9 + c] * xlv[c].x;
                r1 += res_w[o * 9 + c] * xlv[c].y;
            }
            float2 ov;
            ov.x = gelu_fast(val0) + r0;
            ov.y = gelu_fast(val1) + r1;
            *(float2*)&out[xbase + o * plane] = ov;
        }
    }
}

extern "C" void kernel_launch(void* const* d_in, const int* in_sizes, int n_in,
                              void* d_out, int out_size, void* d_ws, size_t ws_size,
                              hipStream_t stream) {
    (void)in_sizes; (void)out_size;
    if (n_in < 19) return;
    const float* xh        = (const float*)d_in[0];
    const float* xl        = (const float*)d_in[1];
    const float* mask      = (const float*)d_in[2];
    const float* pre_w     = (const float*)d_in[3];
    const float* pre_b     = (const float*)d_in[4];
    const float* g_ln_w    = (const float*)d_in[5];
    const float* g_ln_b    = (const float*)d_in[6];
    const float* g_base_w  = (const float*)d_in[7];
    const float* g_base_b  = (const float*)d_in[8];
    const float* g_base_s  = (const float*)d_in[9];
    const float* g_wt_w    = (const float*)d_in[10];
    const float* g_wt_s    = (const float*)d_in[11];
    const float* g_pw_w    = (const float*)d_in[12];
    const float* tail_ln_w = (const float*)d_in[13];
    const float* tail_ln_b = (const float*)d_in[14];
    const float* tail_w    = (const float*)d_in[15];
    const float* tail_b    = (const float*)d_in[16];
    const float* res_w     = (const float*)d_in[17];
    const float* res_b     = (const float*)d_in[18];
    float* outp = (float*)d_out;
    float* ws   = (float*)d_ws;

    if (ws == nullptr || ws_size < WS_NEEDED_BYTES) return;  // harness provides ws

    pre_project_kernel<<<dim3(2048), dim3(256), 0, stream>>>(
        xh, pre_w, pre_b, g_base_w, g_base_b, g_base_s, g_wt_w, g_wt_s,
        tail_ln_w, tail_ln_b, tail_w, tail_b, ws);
    uem_pair_kernel<<<dim3(HL / TS, HL / TS, BB), dim3(16, 16, 1), 0, stream>>>(
        xl, mask, g_ln_w, g_ln_b, g_pw_w, res_w, res_b, ws, outp);
}